// Round 1
// baseline (109.580 us; speedup 1.0000x reference)
//
#include <hip/hip_runtime.h>

#define B_   256
#define T_   192
#define C_   256
#define S_   7      // MAX_NUM_SEG
#define L_   64     // 2*MAX_LEN_SEG
#define PAD_ 192    // MAX_LEN_PAD

__global__ __launch_bounds__(512) void interp_lnr_kernel(
    const float* __restrict__ x,        // [B, T, C]
    const float* __restrict__ scales,   // [B*S]
    const int*   __restrict__ len_seg,  // [B*S]
    const int*   __restrict__ len_seq,  // [B]
    float*       __restrict__ out)      // [B, PAD, C]
{
    __shared__ int   s_idx[PAD_];    // source row per output row
    __shared__ float s_lam[PAD_];    // interp weight per output row
    __shared__ int   s_wavetot[S_];  // valid count per wave (= per segment)
    __shared__ int   s_nvalid;

    const int b   = blockIdx.x;
    const int tid = threadIdx.x;

    // ---------------- Phase A1: per-(seg, l) metadata (448 threads = 7 full waves)
    bool  maskv  = false;
    int   prefix = 0;
    int   wave   = tid >> 6;
    float lam    = 0.0f;
    int   i0     = 0;

    if (tid < S_ * L_) {
        const int s = wave;          // segment index (64 l-values per wave)
        const int l = tid & 63;

        const float scale = scales[b * S_ + s];
        const int   lseg  = len_seg[b * S_ + s];
        int off = 0;
        #pragma unroll
        for (int k = 0; k < S_ - 1; ++k)
            if (k < s) off += len_seg[b * S_ + k];
        const int lsq = len_seq[b];

        const float idx_scaled = (float)l / scale;
        const float idx_fl     = floorf(idx_scaled);
        lam = idx_scaled - idx_fl;
        const float idx_org = idx_fl + (float)off;

        maskv = (idx_fl < (float)(lseg - 1)) && (idx_org < (float)(lsq - 1));

        int ii = (int)idx_org;
        ii = ii < 0 ? 0 : (ii > T_ - 2 ? T_ - 2 : ii);
        i0 = ii;

        const unsigned long long bal  = __ballot(maskv);
        const int                lane = tid & 63;
        prefix = __popcll(bal & ((1ull << lane) - 1ull));
        if (lane == 0) s_wavetot[wave] = __popcll(bal);
    }
    __syncthreads();

    // ---------------- Phase A2: compaction write
    if (tid < S_ * L_) {
        int waveoff = 0;
        #pragma unroll
        for (int k = 0; k < S_ - 1; ++k)
            if (k < wave) waveoff += s_wavetot[k];
        const int pos = waveoff + prefix;
        if (maskv && pos < PAD_) {
            s_idx[pos] = i0;
            s_lam[pos] = lam;
        }
    }
    if (tid == 0) {
        int tot = 0;
        #pragma unroll
        for (int k = 0; k < S_; ++k) tot += s_wavetot[k];
        s_nvalid = tot < PAD_ ? tot : PAD_;
    }
    __syncthreads();

    // ---------------- Phase B: coalesced output write (192 rows x 64 float4)
    const int nvalid = s_nvalid;
    const float*  xb   = x + (size_t)b * T_ * C_;
    float4*       out4 = (float4*)(out + (size_t)b * PAD_ * C_);
    const int     nvec = PAD_ * (C_ / 4);   // 12288 float4 per batch element

    for (int e = tid; e < nvec; e += 512) {
        const int r  = e >> 6;   // output row (C_/4 == 64)
        const int c4 = e & 63;
        float4 v;
        if (r < nvalid) {
            const int   row = s_idx[r];
            const float lm  = s_lam[r];
            const float om  = 1.0f - lm;
            const float4 a = ((const float4*)(xb + (size_t)row       * C_))[c4];
            const float4 c = ((const float4*)(xb + (size_t)(row + 1) * C_))[c4];
            v.x = om * a.x + lm * c.x;
            v.y = om * a.y + lm * c.y;
            v.z = om * a.z + lm * c.z;
            v.w = om * a.w + lm * c.w;
        } else {
            v = make_float4(0.0f, 0.0f, 0.0f, 0.0f);
        }
        out4[e] = v;
    }
}

extern "C" void kernel_launch(void* const* d_in, const int* in_sizes, int n_in,
                              void* d_out, int out_size, void* d_ws, size_t ws_size,
                              hipStream_t stream) {
    const float* x       = (const float*)d_in[0];
    const float* scales  = (const float*)d_in[1];
    const int*   len_seg = (const int*)d_in[2];
    const int*   len_seq = (const int*)d_in[3];
    float*       out     = (float*)d_out;

    interp_lnr_kernel<<<B_, 512, 0, stream>>>(x, scales, len_seg, len_seq, out);
}

// Round 2
// 107.122 us; speedup vs baseline: 1.0229x; 1.0229x over previous
//
#include <hip/hip_runtime.h>

#define B_   256
#define T_   192
#define C_   256
#define S_   7      // MAX_NUM_SEG
#define L_   64     // 2*MAX_LEN_SEG
#define PAD_ 192    // MAX_LEN_PAD
#define K_   4      // row-chunks per batch element (PAD_/K_ rows each)

__global__ __launch_bounds__(512) void interp_lnr_kernel(
    const float* __restrict__ x,        // [B, T, C]
    const float* __restrict__ scales,   // [B*S]
    const int*   __restrict__ len_seg,  // [B*S]
    const int*   __restrict__ len_seq,  // [B]
    float*       __restrict__ out)      // [B, PAD, C]
{
    __shared__ int   s_idx[PAD_];    // source row per output row
    __shared__ float s_lam[PAD_];    // interp weight per output row
    __shared__ int   s_wavetot[S_];  // valid count per segment
    __shared__ int   s_nvalid;

    const int b     = blockIdx.y;
    const int chunk = blockIdx.x;        // 0..K_-1
    const int tid   = threadIdx.x;

    // ---------------- Phase A1: per-(seg, l) metadata (448 threads = 7 full waves)
    bool  maskv  = false;
    int   prefix = 0;
    int   wave   = tid >> 6;
    float lam    = 0.0f;
    int   i0     = 0;

    if (tid < S_ * L_) {
        const int s = wave;          // segment index (64 l-values per wave)
        const int l = tid & 63;

        const float scale = scales[b * S_ + s];
        const int   lseg  = len_seg[b * S_ + s];
        int off = 0;
        #pragma unroll
        for (int k = 0; k < S_ - 1; ++k)
            if (k < s) off += len_seg[b * S_ + k];
        const int lsq = len_seq[b];

        const float idx_scaled = (float)l / scale;
        const float idx_fl     = floorf(idx_scaled);
        lam = idx_scaled - idx_fl;
        const float idx_org = idx_fl + (float)off;

        maskv = (idx_fl < (float)(lseg - 1)) && (idx_org < (float)(lsq - 1));

        int ii = (int)idx_org;
        ii = ii < 0 ? 0 : (ii > T_ - 2 ? T_ - 2 : ii);
        i0 = ii;

        const unsigned long long bal  = __ballot(maskv);
        const int                lane = tid & 63;
        prefix = __popcll(bal & ((1ull << lane) - 1ull));
        if (lane == 0) s_wavetot[wave] = __popcll(bal);
    }
    __syncthreads();

    // ---------------- Phase A2: compaction write into LDS tables
    if (tid < S_ * L_) {
        int waveoff = 0;
        #pragma unroll
        for (int k = 0; k < S_ - 1; ++k)
            if (k < wave) waveoff += s_wavetot[k];
        const int pos = waveoff + prefix;
        if (maskv && pos < PAD_) {
            s_idx[pos] = i0;
            s_lam[pos] = lam;
        }
    }
    if (tid == 0) {
        int tot = 0;
        #pragma unroll
        for (int k = 0; k < S_; ++k) tot += s_wavetot[k];
        s_nvalid = tot < PAD_ ? tot : PAD_;
    }
    __syncthreads();

    // ---------------- Phase B: coalesced output write for this chunk's rows
    const int nvalid = s_nvalid;
    const int r0     = chunk * (PAD_ / K_);              // first row of this chunk
    const float*  xb   = x + (size_t)b * T_ * C_;
    float4*       out4 = (float4*)(out + (size_t)b * PAD_ * C_);
    const int     nvec = (PAD_ / K_) * (C_ / 4);         // 48 * 64 = 3072 float4

    for (int e = tid; e < nvec; e += 512) {
        const int r  = r0 + (e >> 6);   // output row (C_/4 == 64)
        const int c4 = e & 63;
        float4 v;
        if (r < nvalid) {
            const int   row = s_idx[r];
            const float lm  = s_lam[r];
            const float om  = 1.0f - lm;
            const float4 a = ((const float4*)(xb + (size_t)row       * C_))[c4];
            const float4 c = ((const float4*)(xb + (size_t)(row + 1) * C_))[c4];
            v.x = om * a.x + lm * c.x;
            v.y = om * a.y + lm * c.y;
            v.z = om * a.z + lm * c.z;
            v.w = om * a.w + lm * c.w;
        } else {
            v = make_float4(0.0f, 0.0f, 0.0f, 0.0f);
        }
        out4[(size_t)r * (C_ / 4) + c4] = v;
    }
}

extern "C" void kernel_launch(void* const* d_in, const int* in_sizes, int n_in,
                              void* d_out, int out_size, void* d_ws, size_t ws_size,
                              hipStream_t stream) {
    const float* x       = (const float*)d_in[0];
    const float* scales  = (const float*)d_in[1];
    const int*   len_seg = (const int*)d_in[2];
    const int*   len_seq = (const int*)d_in[3];
    float*       out     = (float*)d_out;

    dim3 grid(K_, B_);
    interp_lnr_kernel<<<grid, 512, 0, stream>>>(x, scales, len_seg, len_seq, out);
}

// Round 4
// 105.942 us; speedup vs baseline: 1.0343x; 1.0111x over previous
//
#include <hip/hip_runtime.h>

#define B_   256
#define T_   192
#define C_   256
#define S_   7      // MAX_NUM_SEG
#define L_   64     // 2*MAX_LEN_SEG
#define PAD_ 192    // MAX_LEN_PAD
#define K_   4      // row-chunks per batch element (PAD_/K_ = 48 rows each)
#define RPT_ 6      // 48 rows * 64 f4 / 512 threads

typedef float f4 __attribute__((ext_vector_type(4)));  // native vector: NT-store-able

__global__ __launch_bounds__(512) void interp_lnr_kernel(
    const float* __restrict__ x,        // [B, T, C]
    const float* __restrict__ scales,   // [B*S]
    const int*   __restrict__ len_seg,  // [B*S]
    const int*   __restrict__ len_seq,  // [B]
    float*       __restrict__ out)      // [B, PAD, C]
{
    __shared__ int   s_idx[PAD_];    // source row per output row
    __shared__ float s_lam[PAD_];    // interp weight per output row
    __shared__ int   s_wavetot[S_];  // valid count per segment
    __shared__ int   s_nvalid;

    const int b     = blockIdx.y;
    const int chunk = blockIdx.x;        // 0..K_-1
    const int tid   = threadIdx.x;

    // ---------------- Phase A1: per-(seg, l) metadata (448 threads = 7 full waves)
    bool  maskv  = false;
    int   prefix = 0;
    int   wave   = tid >> 6;
    float lam    = 0.0f;
    int   i0     = 0;

    if (tid < S_ * L_) {
        const int s = wave;          // segment index (64 l-values per wave)
        const int l = tid & 63;

        const float scale = scales[b * S_ + s];
        const int   lseg  = len_seg[b * S_ + s];
        int off = 0;
        #pragma unroll
        for (int k = 0; k < S_ - 1; ++k)
            if (k < s) off += len_seg[b * S_ + k];
        const int lsq = len_seq[b];

        const float idx_scaled = (float)l / scale;
        const float idx_fl     = floorf(idx_scaled);
        lam = idx_scaled - idx_fl;
        const float idx_org = idx_fl + (float)off;

        maskv = (idx_fl < (float)(lseg - 1)) && (idx_org < (float)(lsq - 1));

        int ii = (int)idx_org;
        ii = ii < 0 ? 0 : (ii > T_ - 2 ? T_ - 2 : ii);
        i0 = ii;

        const unsigned long long bal  = __ballot(maskv);
        const int                lane = tid & 63;
        prefix = __popcll(bal & ((1ull << lane) - 1ull));
        if (lane == 0) s_wavetot[wave] = __popcll(bal);
    }
    __syncthreads();

    // ---------------- Phase A2: compaction write into LDS tables
    if (tid < S_ * L_) {
        int waveoff = 0;
        #pragma unroll
        for (int k = 0; k < S_ - 1; ++k)
            if (k < wave) waveoff += s_wavetot[k];
        const int pos = waveoff + prefix;
        if (maskv && pos < PAD_) {
            s_idx[pos] = i0;
            s_lam[pos] = lam;
        }
    }
    if (tid == 0) {
        int tot = 0;
        #pragma unroll
        for (int k = 0; k < S_; ++k) tot += s_wavetot[k];
        s_nvalid = tot < PAD_ ? tot : PAD_;
    }
    __syncthreads();

    // ---------------- Phase B: coalesced output write for this chunk's rows.
    // Prefetch row metadata from LDS, then issue all global loads before any
    // FMA/store (max in-flight vmcnt), then blend + non-temporal store.
    const int nvalid = s_nvalid;
    const int r0     = chunk * (PAD_ / K_);              // first row of this chunk
    const int rbase  = r0 + (tid >> 6);                  // this thread's first row
    const int c4     = tid & 63;
    const float* xb   = x + (size_t)b * T_ * C_;
    f4*          out4 = (f4*)(out + (size_t)b * PAD_ * C_);

    int   rows[RPT_];
    float lms [RPT_];
    bool  val [RPT_];
    #pragma unroll
    for (int i = 0; i < RPT_; ++i) {
        const int r = rbase + i * 8;                     // 8 rows per 512-thread pass
        val[i]  = (r < nvalid);
        rows[i] = val[i] ? s_idx[r] : 0;
        lms[i]  = val[i] ? s_lam[r] : 0.0f;
    }

    f4 lo[RPT_], hi[RPT_];
    #pragma unroll
    for (int i = 0; i < RPT_; ++i) {
        const int row = rows[i];
        lo[i] = ((const f4*)(xb + (size_t)row       * C_))[c4];
        hi[i] = ((const f4*)(xb + (size_t)(row + 1) * C_))[c4];
    }

    #pragma unroll
    for (int i = 0; i < RPT_; ++i) {
        const int r = rbase + i * 8;
        f4 v;
        if (val[i]) {
            const float lm = lms[i];
            const float om = 1.0f - lm;
            v = om * lo[i] + lm * hi[i];
        } else {
            v = (f4)(0.0f);
        }
        __builtin_nontemporal_store(v, &out4[(size_t)r * (C_ / 4) + c4]);
    }
}

extern "C" void kernel_launch(void* const* d_in, const int* in_sizes, int n_in,
                              void* d_out, int out_size, void* d_ws, size_t ws_size,
                              hipStream_t stream) {
    const float* x       = (const float*)d_in[0];
    const float* scales  = (const float*)d_in[1];
    const int*   len_seg = (const int*)d_in[2];
    const int*   len_seq = (const int*)d_in[3];
    float*       out     = (float*)d_out;

    dim3 grid(K_, B_);
    interp_lnr_kernel<<<grid, 512, 0, stream>>>(x, scales, len_seg, len_seq, out);
}

// Round 5
// 105.889 us; speedup vs baseline: 1.0349x; 1.0005x over previous
//
#include <hip/hip_runtime.h>

#define B_   256
#define T_   192
#define C_   256
#define S_   7      // MAX_NUM_SEG
#define L_   64     // 2*MAX_LEN_SEG
#define PAD_ 192    // MAX_LEN_PAD
#define K_   8      // row-chunks per batch element (PAD_/K_ = 24 rows each)
#define RPT_ 3      // 24 rows * 64 f4 / 512 threads

typedef float f4 __attribute__((ext_vector_type(4)));  // native vector: NT-store-able

__global__ __launch_bounds__(512, 4) void interp_lnr_kernel(
    const float* __restrict__ x,        // [B, T, C]
    const float* __restrict__ scales,   // [B*S]
    const int*   __restrict__ len_seg,  // [B*S]
    const int*   __restrict__ len_seq,  // [B]
    float*       __restrict__ out)      // [B, PAD, C]
{
    __shared__ int   s_idx[PAD_];    // source row per output row
    __shared__ float s_lam[PAD_];    // interp weight per output row
    __shared__ int   s_wavetot[S_];  // valid count per segment
    __shared__ int   s_nvalid;

    const int b     = blockIdx.y;
    const int chunk = blockIdx.x;        // 0..K_-1
    const int tid   = threadIdx.x;

    // ---------------- Phase A1: per-(seg, l) metadata (448 threads = 7 full waves)
    bool  maskv  = false;
    int   prefix = 0;
    int   wave   = tid >> 6;
    float lam    = 0.0f;
    int   i0     = 0;

    if (tid < S_ * L_) {
        const int s = wave;          // segment index (64 l-values per wave)
        const int l = tid & 63;

        const float scale = scales[b * S_ + s];
        const int   lseg  = len_seg[b * S_ + s];
        int off = 0;
        #pragma unroll
        for (int k = 0; k < S_ - 1; ++k)
            if (k < s) off += len_seg[b * S_ + k];
        const int lsq = len_seq[b];

        const float idx_scaled = (float)l / scale;
        const float idx_fl     = floorf(idx_scaled);
        lam = idx_scaled - idx_fl;
        const float idx_org = idx_fl + (float)off;

        maskv = (idx_fl < (float)(lseg - 1)) && (idx_org < (float)(lsq - 1));

        int ii = (int)idx_org;
        ii = ii < 0 ? 0 : (ii > T_ - 2 ? T_ - 2 : ii);
        i0 = ii;

        const unsigned long long bal  = __ballot(maskv);
        const int                lane = tid & 63;
        prefix = __popcll(bal & ((1ull << lane) - 1ull));
        if (lane == 0) s_wavetot[wave] = __popcll(bal);
    }
    __syncthreads();

    // ---------------- Phase A2: compaction write into LDS tables
    if (tid < S_ * L_) {
        int waveoff = 0;
        #pragma unroll
        for (int k = 0; k < S_ - 1; ++k)
            if (k < wave) waveoff += s_wavetot[k];
        const int pos = waveoff + prefix;
        if (maskv && pos < PAD_) {
            s_idx[pos] = i0;
            s_lam[pos] = lam;
        }
    }
    if (tid == 0) {
        int tot = 0;
        #pragma unroll
        for (int k = 0; k < S_; ++k) tot += s_wavetot[k];
        s_nvalid = tot < PAD_ ? tot : PAD_;
    }
    __syncthreads();

    // ---------------- Phase B: coalesced output write for this chunk's rows.
    // RPT_=3 keeps only 6 f4 loads in flight -> ~64 VGPR -> 4 blocks/CU.
    const int nvalid = s_nvalid;
    const int r0     = chunk * (PAD_ / K_);              // first row of this chunk
    const int rbase  = r0 + (tid >> 6);                  // this thread's first row
    const int c4     = tid & 63;
    const float* xb   = x + (size_t)b * T_ * C_;
    f4*          out4 = (f4*)(out + (size_t)b * PAD_ * C_);

    int   rows[RPT_];
    float lms [RPT_];
    bool  val [RPT_];
    #pragma unroll
    for (int i = 0; i < RPT_; ++i) {
        const int r = rbase + i * 8;                     // 8 rows per 512-thread pass
        val[i]  = (r < nvalid);
        rows[i] = val[i] ? s_idx[r] : 0;
        lms[i]  = val[i] ? s_lam[r] : 0.0f;
    }

    f4 lo[RPT_], hi[RPT_];
    #pragma unroll
    for (int i = 0; i < RPT_; ++i) {
        const int row = rows[i];
        lo[i] = ((const f4*)(xb + (size_t)row       * C_))[c4];
        hi[i] = ((const f4*)(xb + (size_t)(row + 1) * C_))[c4];
    }

    #pragma unroll
    for (int i = 0; i < RPT_; ++i) {
        const int r = rbase + i * 8;
        f4 v;
        if (val[i]) {
            const float lm = lms[i];
            const float om = 1.0f - lm;
            v = om * lo[i] + lm * hi[i];
        } else {
            v = (f4)(0.0f);
        }
        __builtin_nontemporal_store(v, &out4[(size_t)r * (C_ / 4) + c4]);
    }
}

extern "C" void kernel_launch(void* const* d_in, const int* in_sizes, int n_in,
                              void* d_out, int out_size, void* d_ws, size_t ws_size,
                              hipStream_t stream) {
    const float* x       = (const float*)d_in[0];
    const float* scales  = (const float*)d_in[1];
    const int*   len_seg = (const int*)d_in[2];
    const int*   len_seq = (const int*)d_in[3];
    float*       out     = (float*)d_out;

    dim3 grid(K_, B_);
    interp_lnr_kernel<<<grid, 512, 0, stream>>>(x, scales, len_seg, len_seq, out);
}